// Round 11
// baseline (219.607 us; speedup 1.0000x reference)
//
#include <hip/hip_runtime.h>

#define DIM   1024
#define LPR   32            // lanes cooperating on one row (2 rows per wave)
#define SEG   (DIM / LPR)   // 32 floats per lane
#define SEG4  (SEG / 4)     // 8 float4 per lane
#define WAVES_PER_BLOCK 4
#define PAIRS_PER_WAVE  8   // row-pairs each wave streams through

typedef float f32x4 __attribute__((ext_vector_type(4)));
#define AS1 __attribute__((address_space(1)))
#define AS3 __attribute__((address_space(3)))

// ---------------- kernel 1: cos/sin table -> d_ws (NATURAL order) ----------
// ws[j] = (cos a_j, sin a_j). Lane t's steps are j = t*32..t*32+31, i.e. 16
// contiguous float4 per lane -> hoisted into registers once per wave.
__global__ void qll_table(const float* __restrict__ angles, float2* __restrict__ ws) {
    int j = blockIdx.x * blockDim.x + threadIdx.x;
    if (j < DIM) {
        float a = angles[j];
        ws[j] = make_float2(cosf(a), sinf(a));
    }
}

// ---------------- main kernel ----------------------------------------------
// Row recurrence (Givens sweep): carry = value of column i entering step i.
//   out[i] = c_i*carry - s_i*v[i+1];  carry' = s_i*carry + c_i*v[i+1]
// Affine in carry -> per-lane (A,B) + width-32 shfl scan (the wave's two rows
// scan in parallel).
//
// vs r10 — DS-pipe diet targeted at the measured ~850 DS cyc/pair:
//  * cs table hoisted to 64 VGPRs ONCE per wave (16 b128 loads from the
//    natural-order d_ws table), reused across all 8 streamed pairs. Deletes
//    64 ds_read_b64 per pair (~45% of DS traffic), the 8KB cs LDS buffer,
//    and ALL barriers (nothing block-shared remains).
//  * everything else (dbuf glds pipeline, counted vmcnt, LDS out-transpose,
//    nt stores) is r10 verbatim.
__global__ __launch_bounds__(256, 2)
void qll_kernel(const float* __restrict__ x,
                const float2* __restrict__ csws,
                float* __restrict__ out,
                int batch)
{
    __shared__ f32x4 stage[WAVES_PER_BLOCK][2][512];  // 64 KB, wave-private dbuf

    const int tid  = threadIdx.x;
    const int l    = tid & 63;        // lane in wave
    const int wave = tid >> 6;        // 0..3
    const int h    = (tid >> 5) & 1;  // which row of the pair
    const int t    = tid & 31;        // segment index within row
    const int swz_l = l ^ ((l >> 3) & 7);   // involution on f32x4 index

    const int pairBase = (blockIdx.x * WAVES_PER_BLOCK + wave) * PAIRS_PER_WAVE;
    const int pairsTot = batch >> 1;
    int np = pairsTot - pairBase;
    if (np < 0) np = 0;
    if (np > PAIRS_PER_WAVE) np = PAIRS_PER_WAVE;

    // ---- cs -> registers, once per wave: csr[ii]=(c2ii,s2ii,c2ii+1,s2ii+1) ----
    const f32x4* ws4 = reinterpret_cast<const f32x4*>(csws) + t * 16;
    f32x4 csr[16];
#pragma unroll
    for (int ii = 0; ii < 16; ++ii) csr[ii] = ws4[ii];
    float2 w0 = csws[0];                        // step 0 (uniform)
    __builtin_amdgcn_sched_barrier(0);          // pin: csr loads oldest in vmcnt order

    // ---- prime the pipeline: pairs 0 and 1 ----
    const f32x4* ginb = reinterpret_cast<const f32x4*>(x);
    if (np > 0) {
        const f32x4* g = ginb + (size_t)pairBase * 512;
#pragma unroll
        for (int m = 0; m < 8; ++m)
            __builtin_amdgcn_global_load_lds((const AS1 void*)(g + m * 64 + swz_l),
                                             (AS3 void*)(&stage[wave][0][m * 64]), 16, 0, 0);
    }
    if (np > 1) {
        const f32x4* g = ginb + (size_t)(pairBase + 1) * 512;
#pragma unroll
        for (int m = 0; m < 8; ++m)
            __builtin_amdgcn_global_load_lds((const AS1 void*)(g + m * 64 + swz_l),
                                             (AS3 void*)(&stage[wave][1][m * 64]), 16, 0, 0);
    }
    if (np <= 0) return;

    f32x4* goutb = reinterpret_cast<f32x4*>(out);

    for (int it = 0; it < np; ++it) {
        f32x4* buf = stage[wave][it & 1];

        // ---- counted wait: glds(it) retired (vmcnt retires in issue order;
        //      csr loads are oldest and thus also drained by iter 0's wait) ----
        if (it == 0) {
            if (np > 1) { asm volatile("s_waitcnt vmcnt(8)"  ::: "memory"); }
            else        { asm volatile("s_waitcnt vmcnt(0)"  ::: "memory"); }
        } else if (it + 1 < np) {
            asm volatile("s_waitcnt vmcnt(16)" ::: "memory");
        } else {
            asm volatile("s_waitcnt vmcnt(8)"  ::: "memory");
        }
        __builtin_amdgcn_sched_barrier(0);

        // ---- read this lane's 32-float segment (bank-balanced b128s) ----
        float v[SEG];
#pragma unroll
        for (int e = 0; e < SEG4; ++e) {
            f32x4 q = buf[h * 256 + t * 8 + (e ^ (t & 7))];
            v[4*e+0] = q.x; v[4*e+1] = q.y; v[4*e+2] = q.z; v[4*e+3] = q.w;
        }

        // boundary exchanges (capture BEFORE phase 2 overwrites v[])
        float v0row = __shfl(v[0], 0, LPR);        // row's original column 0
        float v1row = __shfl(v[1], 0, LPR);
        float vnext = __shfl_down(v[0], 1, LPR);   // next lane's first elem

        // ---- phase 1: per-lane affine (A,B) with carry_in = 0 ----
        float A = 1.f, B = 0.f;
#pragma unroll
        for (int ii = 0; ii < 16; ++ii) {
            f32x4 q = csr[ii];                  // (c,s) of steps 2ii, 2ii+1
            B = q.y * B + q.x * v[2*ii + 1];    // step 2ii
            A = q.y * A;
            float vn = (ii == 15) ? vnext : v[2*ii + 2];
            B = q.w * B + q.z * vn;             // step 2ii+1 (lane31@ii=15: unused)
            A = q.w * A;
        }

        // ---- inclusive affine scan across 32 lanes (both rows in parallel) ----
#pragma unroll
        for (int d = 1; d < LPR; d <<= 1) {
            float pa = __shfl_up(A, d, LPR);
            float pb = __shfl_up(B, d, LPR);
            if (t >= d) { B = A * pb + B; A = A * pa; }
        }
        // exclusive prefix -> carry entering this lane's segment
        float ea = __shfl_up(A, 1, LPR);
        float eb = __shfl_up(B, 1, LPR);
        if (t == 0) { ea = 1.f; eb = 0.f; }
        float carry = ea * v0row + eb;

        // provisional out[0] (result of step 0), consumed by wrap step 1023
        float out0_prov = w0.x * v0row - w0.y * v1row;

        // ---- phase 2: replay with true carry, outputs into v[] ----
#pragma unroll
        for (int ii = 0; ii < 16; ++ii) {
            f32x4 q = csr[ii];
            float vn0 = v[2*ii + 1];
            float o0  = q.x * carry - q.y * vn0;      // out[2ii]
            carry     = q.y * carry + q.x * vn0;
            v[2*ii] = o0;
            float vn1 = (ii == 15) ? ((t == LPR - 1) ? out0_prov : vnext)
                                   : v[2*ii + 2];
            float o1  = q.z * carry - q.w * vn1;      // out[2ii+1]
            carry     = q.w * carry + q.z * vn1;      // lane31@ii=15: final col0
            v[2*ii + 1] = o1;
        }
        float out0_final = __shfl(carry, LPR - 1, LPR);  // lane 31 -> all
        if (t == 0) v[0] = out0_final;

        // ---- out-stage into buf (same-wave DS pipe in-order), then
        //      coalesced nontemporal stores ----
#pragma unroll
        for (int e = 0; e < SEG4; ++e) {
            f32x4 q = { v[4*e+0], v[4*e+1], v[4*e+2], v[4*e+3] };
            buf[h * 256 + t * 8 + (e ^ (t & 7))] = q;
        }
        f32x4* gout = goutb + (size_t)(pairBase + it) * 512;
#pragma unroll
        for (int m = 0; m < 8; ++m) {
            f32x4 q = buf[m * 64 + swz_l];
            __builtin_nontemporal_store(q, gout + m * 64 + l);
        }

        // ---- issue glds for pair it+2 into THIS buffer, strictly after the
        //      stores' ds_reads (sched_barrier pins the boundary) ----
        __builtin_amdgcn_sched_barrier(0);
        if (it + 2 < np) {
            const f32x4* g = ginb + (size_t)(pairBase + it + 2) * 512;
#pragma unroll
            for (int m = 0; m < 8; ++m)
                __builtin_amdgcn_global_load_lds((const AS1 void*)(g + m * 64 + swz_l),
                                                 (AS3 void*)(&buf[m * 64]), 16, 0, 0);
        }
    }
}

// ---------------- fallback (ws too small): r6-style self-contained ---------
__global__ __launch_bounds__(256, 4)
void qll_kernel_fb(const float* __restrict__ x,
                   const float* __restrict__ angles,
                   float* __restrict__ out,
                   int batch)
{
    __shared__ float2 cs[DIM];
    __shared__ f32x4  stage[WAVES_PER_BLOCK][512];

    const int tid  = threadIdx.x;
    const int l    = tid & 63;
    const int wave = tid >> 6;
    const int h    = (tid >> 5) & 1;
    const int t    = tid & 31;
    const int r0   = blockIdx.x * (WAVES_PER_BLOCK * 2) + wave * 2;
    const bool active = (r0 + 2 <= batch);
    const int swz_l = l ^ ((l >> 3) & 7);

    for (int loc = tid; loc < DIM; loc += 256) {
        int j = ((loc & 31) << 5) | (loc >> 5);
        float a = angles[j];
        cs[loc] = make_float2(cosf(a), sinf(a));
    }
    __syncthreads();
    if (!active) return;

    const f32x4* gin = reinterpret_cast<const f32x4*>(x) + (size_t)r0 * 256;
#pragma unroll
    for (int m = 0; m < 8; ++m) {
        __builtin_amdgcn_global_load_lds(
            (const AS1 void*)(gin + m * 64 + swz_l),
            (AS3 void*)(&stage[wave][m * 64]), 16, 0, 0);
    }
    asm volatile("s_waitcnt vmcnt(0)" ::: "memory");
    __builtin_amdgcn_sched_barrier(0);

    float v[SEG];
#pragma unroll
    for (int e = 0; e < SEG4; ++e) {
        f32x4 q = stage[wave][h * 256 + t * 8 + (e ^ (t & 7))];
        v[4*e+0] = q.x; v[4*e+1] = q.y; v[4*e+2] = q.z; v[4*e+3] = q.w;
    }
    float v0row = __shfl(v[0], 0, LPR);
    float v1row = __shfl(v[1], 0, LPR);
    float vnext = __shfl_down(v[0], 1, LPR);

    float A = 1.f, B = 0.f;
#pragma unroll
    for (int i = 0; i < SEG - 1; ++i) {
        float2 w = cs[i * LPR + t];
        B = w.y * B + w.x * v[i + 1];
        A = w.y * A;
    }
    {
        float2 w = cs[(SEG - 1) * LPR + t];
        B = w.y * B + w.x * vnext;
        A = w.y * A;
    }
#pragma unroll
    for (int d = 1; d < LPR; d <<= 1) {
        float pa = __shfl_up(A, d, LPR);
        float pb = __shfl_up(B, d, LPR);
        if (t >= d) { B = A * pb + B; A = A * pa; }
    }
    float ea = __shfl_up(A, 1, LPR);
    float eb = __shfl_up(B, 1, LPR);
    if (t == 0) { ea = 1.f; eb = 0.f; }
    float carry = ea * v0row + eb;

    float2 w0 = cs[0];
    float out0_prov = w0.x * v0row - w0.y * v1row;

#pragma unroll
    for (int i = 0; i < SEG - 1; ++i) {
        float2 w = cs[i * LPR + t];
        float vn = v[i + 1];
        float o  = w.x * carry - w.y * vn;
        carry    = w.y * carry + w.x * vn;
        v[i] = o;
    }
    {
        float2 w  = cs[(SEG - 1) * LPR + t];
        float vn  = (t == LPR - 1) ? out0_prov : vnext;
        float o   = w.x * carry - w.y * vn;
        float nc  = w.y * carry + w.x * vn;
        v[SEG - 1] = o;
        float out0_final = __shfl(nc, LPR - 1, LPR);
        if (t == 0) v[0] = out0_final;
    }
#pragma unroll
    for (int e = 0; e < SEG4; ++e) {
        f32x4 q = { v[4*e+0], v[4*e+1], v[4*e+2], v[4*e+3] };
        stage[wave][h * 256 + t * 8 + (e ^ (t & 7))] = q;
    }
    f32x4* gout = reinterpret_cast<f32x4*>(out) + (size_t)r0 * 256;
#pragma unroll
    for (int m = 0; m < 8; ++m) {
        f32x4 q = stage[wave][m * 64 + swz_l];
        __builtin_nontemporal_store(q, gout + m * 64 + l);
    }
}

extern "C" void kernel_launch(void* const* d_in, const int* in_sizes, int n_in,
                              void* d_out, int out_size, void* d_ws, size_t ws_size,
                              hipStream_t stream) {
    const float* x      = (const float*)d_in[0];
    const float* angles = (const float*)d_in[1];
    float* outp         = (float*)d_out;

    int batch = in_sizes[0] / DIM;   // 65536

    if (ws_size >= (size_t)(DIM * sizeof(float2))) {
        float2* ws = (float2*)d_ws;
        qll_table<<<(DIM + 255) / 256, 256, 0, stream>>>(angles, ws);
        int pairs = batch / 2;                                   // 32768
        int perBlock = WAVES_PER_BLOCK * PAIRS_PER_WAVE;         // 32
        int grid = (pairs + perBlock - 1) / perBlock;            // 1024
        qll_kernel<<<grid, 256, 0, stream>>>(x, ws, outp, batch);
    } else {
        int rowsPerBlock = WAVES_PER_BLOCK * 2;
        int grid = (batch + rowsPerBlock - 1) / rowsPerBlock;
        qll_kernel_fb<<<grid, 256, 0, stream>>>(x, angles, outp, batch);
    }
}